// Round 18
// baseline (235.188 us; speedup 1.0000x reference)
//
#include <hip/hip_runtime.h>

// B=2,H=16,L=2048,D=64 attention, outputs (out[B,H,L,D], score[B,H,L,L]) fp32.
// Budget: attn ~145us carrying 554MB NT stores + prep ~12us + mask ~5us.
//
// v15 = v13 (best, 169.4us) + KTG=4 retest with occupancy confound removed:
// round-14's KTG=4 used 40960B LDS -> 4 blocks = exactly 160KiB (likely 3
// blk/CU). Now: cs_lds dropped (colsum via global atomics, L2-local per bh
// thanks to XCD swizzle), LDS = 32KB -> 4 blk/CU, fully barrier-free, and
// each row's burst = 8 consecutive 128B chunk stores = 1KB contiguous.
// Ledger: NT required; 512B bursts +22us; 2rowx512B lane layout -10us (rev);
// K-staging/Q-prep/prep-coalescing neutral.

#define L_ 2048
#define D_ 64
#define BH_ 32
#define NKT 32
#define KTG 4

typedef __attribute__((ext_vector_type(8))) short bf16x8;
typedef __attribute__((ext_vector_type(4))) float f32x4;

__device__ __forceinline__ unsigned short f2bf(float f) {
  unsigned u = __builtin_bit_cast(unsigned, f);
  u = (u + 0x7FFFu + ((u >> 16) & 1u)) >> 16;  // RNE
  return (unsigned short)u;
}
__device__ __forceinline__ float bf2f(unsigned short h) {
  unsigned u = ((unsigned)h) << 16;
  return __builtin_bit_cast(float, u);
}

// prep: per 64x64 tile (1024 tiles = bh*32+kt):
//   K -> bf16 fragment-linear tile (el off = (t*2+h)*512 + lg*128 + lc*8 + j)
//   V -> VT (transpose) in the same fragment-linear layout (rows=d, cols=k)
// Built in LDS, then written with linear 16B/lane stores. Zeroes colsum.
__global__ void prep(const float* __restrict__ k, const float* __restrict__ v,
                     unsigned short* __restrict__ wkf, unsigned short* __restrict__ wvf,
                     float* __restrict__ colsum) {
  __shared__ __align__(16) unsigned short kimg[4096];
  __shared__ __align__(16) unsigned short vimg[4096];
  const int bid = blockIdx.x, tid = threadIdx.x;

  if (bid < 64) {
    float* cz = colsum + bid * 1024;
    for (int i = tid; i < 1024; i += 256) cz[i] = 0.0f;
  }

  const float* ks = k + (size_t)bid * 64 * D_;
  const float* vs = v + (size_t)bid * 64 * D_;

  // K tile -> frag-linear LDS image
#pragma unroll
  for (int it = 0; it < 2; ++it) {
    int e8 = it * 256 + tid;      // [0,512)
    int r = e8 >> 3;              // row 0..63
    int c0 = (e8 & 7) * 8;        // col 0,8,..,56
    float4 f0 = *reinterpret_cast<const float4*>(ks + r * D_ + c0);
    float4 f1 = *reinterpret_cast<const float4*>(ks + r * D_ + c0 + 4);
    int t = r >> 4, lc = r & 15, h = c0 >> 5, lg = (c0 & 31) >> 3;
    unsigned short* p = kimg + (t * 2 + h) * 512 + lg * 128 + lc * 8;
    ushort4 u0{f2bf(f0.x), f2bf(f0.y), f2bf(f0.z), f2bf(f0.w)};
    ushort4 u1{f2bf(f1.x), f2bf(f1.y), f2bf(f1.z), f2bf(f1.w)};
    *reinterpret_cast<ushort4*>(p) = u0;
    *reinterpret_cast<ushort4*>(p + 4) = u1;
  }

  // V tile -> transpose directly into frag-linear LDS image (rows=d, cols=k)
#pragma unroll
  for (int it = 0; it < 4; ++it) {
    int e4 = it * 256 + tid;       // 1024 float4
    int kk = e4 >> 4;              // k row 0..63
    int c = (e4 & 15) * 4;         // d cols c..c+3
    float4 f = *reinterpret_cast<const float4*>(vs + kk * D_ + c);
    int h = kk >> 5, lg = (kk >> 3) & 3, j = kk & 7;
    float ff[4] = {f.x, f.y, f.z, f.w};
#pragma unroll
    for (int x = 0; x < 4; ++x) {
      int d = c + x;
      int t = d >> 4, lc = d & 15;
      vimg[(t * 2 + h) * 512 + lg * 128 + lc * 8 + j] = f2bf(ff[x]);
    }
  }
  __syncthreads();

  // blast both images linearly: 16B/lane, full lines
  uint4* kd = reinterpret_cast<uint4*>(wkf + (size_t)bid * 4096);
  uint4* vd = reinterpret_cast<uint4*>(wvf + (size_t)bid * 4096);
  const uint4* ki = reinterpret_cast<const uint4*>(kimg);
  const uint4* vi = reinterpret_cast<const uint4*>(vimg);
#pragma unroll
  for (int it = 0; it < 2; ++it) {
    int idx = it * 256 + tid;      // 512 x 16B chunks per tile
    kd[idx] = ki[idx];
    vd[idx] = vi[idx];
  }
}

__launch_bounds__(256, 4)
__global__ void attn_main(const float* __restrict__ qf,
                          const unsigned short* __restrict__ wkf,
                          const unsigned short* __restrict__ wvf,
                          float* __restrict__ outp,
                          float* __restrict__ score,
                          float* __restrict__ colsum) {
  __shared__ __align__(16) unsigned short ps[4][KTG][1024];  // per-wave P stage (32KB)

  const int tid = threadIdx.x;
  const int w = tid >> 6, lane = tid & 63;
  const int lg = lane >> 4, lc = lane & 15;

  // XCD-chunked swizzle: 1024 blocks -> 128 consecutive per XCD (4 bh per XCD)
  const int bid = (blockIdx.x & 7) * 128 + (blockIdx.x >> 3);
  const int bh = bid >> 5;
  const int qt = bid & 31;

  // Q fragments: fp32 global -> bf16 regs, fold 1/sqrt(64). 16 rows per wave.
  const float* qg = qf + ((size_t)bh * L_ + (size_t)qt * 64 + w * 16) * D_;
  bf16x8 aq[2];
#pragma unroll
  for (int h = 0; h < 2; ++h) {
    const float* r = qg + lc * D_ + h * 32 + lg * 8;
    float4 f0 = *reinterpret_cast<const float4*>(r);
    float4 f1 = *reinterpret_cast<const float4*>(r + 4);
    bf16x8 a;
    a[0] = (short)f2bf(f0.x * 0.125f); a[1] = (short)f2bf(f0.y * 0.125f);
    a[2] = (short)f2bf(f0.z * 0.125f); a[3] = (short)f2bf(f0.w * 0.125f);
    a[4] = (short)f2bf(f1.x * 0.125f); a[5] = (short)f2bf(f1.y * 0.125f);
    a[6] = (short)f2bf(f1.z * 0.125f); a[7] = (short)f2bf(f1.w * 0.125f);
    aq[h] = a;
  }

  const unsigned short* kg = wkf + (size_t)bh * NKT * 4096 + lg * 128 + lc * 8;
  const unsigned short* vg = wvf + (size_t)bh * NKT * 4096 + lg * 128 + lc * 8;

  // ---------------- sweep 1: row sums of exp(s) (no max) ----------------
  float lp[4] = {0.f, 0.f, 0.f, 0.f};

#pragma unroll 2
  for (int kt = 0; kt < NKT; ++kt) {
    const unsigned short* kb = kg + kt * 4096;
    f32x4 s[4];
#pragma unroll
    for (int t = 0; t < 4; ++t) s[t] = f32x4{0.f, 0.f, 0.f, 0.f};
#pragma unroll
    for (int t = 0; t < 4; ++t) {
      bf16x8 b0 = *reinterpret_cast<const bf16x8*>(kb + (t * 2 + 0) * 512);
      bf16x8 b1 = *reinterpret_cast<const bf16x8*>(kb + (t * 2 + 1) * 512);
      s[t] = __builtin_amdgcn_mfma_f32_16x16x32_bf16(aq[0], b0, s[t], 0, 0, 0);
      s[t] = __builtin_amdgcn_mfma_f32_16x16x32_bf16(aq[1], b1, s[t], 0, 0, 0);
    }
#pragma unroll
    for (int t = 0; t < 4; ++t)
#pragma unroll
      for (int r = 0; r < 4; ++r) lp[r] += __expf(s[t][r]);
  }

  float linv[4];
#pragma unroll
  for (int r = 0; r < 4; ++r) {
    float v = lp[r];
    v += __shfl_xor(v, 1);
    v += __shfl_xor(v, 2);
    v += __shfl_xor(v, 4);
    v += __shfl_xor(v, 8);
    linv[r] = 1.0f / v;
  }

  // ------- sweep 2: KTG=4 batches; stage 4 P tiles, 1KB/row burst stores --
  f32x4 o[4];
#pragma unroll
  for (int dt = 0; dt < 4; ++dt) o[dt] = f32x4{0.f, 0.f, 0.f, 0.f};

  float* scoreW = score + ((size_t)bh * L_ + (size_t)qt * 64 + w * 16) * L_;
  float* csb = colsum + bh * L_;

#pragma unroll 1
  for (int ktg = 0; ktg < NKT / KTG; ++ktg) {
#pragma unroll
    for (int half = 0; half < KTG; ++half) {
      const int kt = ktg * KTG + half;
      const unsigned short* kb = kg + kt * 4096;
      char* pw = (char*)ps[w][half];

      f32x4 s[4];
#pragma unroll
      for (int t = 0; t < 4; ++t) s[t] = f32x4{0.f, 0.f, 0.f, 0.f};
#pragma unroll
      for (int t = 0; t < 4; ++t) {
        bf16x8 b0 = *reinterpret_cast<const bf16x8*>(kb + (t * 2 + 0) * 512);
        bf16x8 b1 = *reinterpret_cast<const bf16x8*>(kb + (t * 2 + 1) * 512);
        s[t] = __builtin_amdgcn_mfma_f32_16x16x32_bf16(aq[0], b0, s[t], 0, 0, 0);
        s[t] = __builtin_amdgcn_mfma_f32_16x16x32_bf16(aq[1], b1, s[t], 0, 0, 0);
      }

      // P = exp(s)*linv -> bf16 stage + column partials
      float ct[4] = {0.f, 0.f, 0.f, 0.f};
#pragma unroll
      for (int t = 0; t < 4; ++t)
#pragma unroll
        for (int r = 0; r < 4; ++r) {
          float p = __expf(s[t][r]) * linv[r];
          ct[t] += p;
          int prow = lg * 4 + r;
          unsigned off = ((unsigned)(prow * 128 + (t * 16 + lc) * 2)) ^ (((unsigned)(prow & 7)) << 4);
          *reinterpret_cast<unsigned short*>(pw + off) = f2bf(p);
        }

      // colsum: direct global atomics (L2-local per bh), wave-staggered
#pragma unroll
      for (int t = 0; t < 4; ++t) {
        int tt = (t + w) & 3;
        float c = ct[tt];
        c += __shfl_xor(c, 16);
        c += __shfl_xor(c, 32);
        if (lane < 16) atomicAdd(csb + kt * 64 + tt * 16 + lane, c);
      }

      // P@V: A from this tile's stage, B direct from L2 frag tiles
#pragma unroll
      for (int kk = 0; kk < 2; ++kk) {
        unsigned o0 = ((unsigned)(lc * 128 + kk * 64 + lg * 16)) ^ (((unsigned)(lc & 7)) << 4);
        bf16x8 pa = *reinterpret_cast<const bf16x8*>(pw + o0);
        const unsigned short* vb = vg + kt * 4096 + kk * 512;
#pragma unroll
        for (int dt = 0; dt < 4; ++dt) {
          bf16x8 bv = *reinterpret_cast<const bf16x8*>(vb + dt * 1024);
          o[dt] = __builtin_amdgcn_mfma_f32_16x16x32_bf16(pa, bv, o[dt], 0, 0, 0);
        }
      }
    }

    // burst stores: per row-group, 8 consecutive 128B chunk stores = 1KB/row
#pragma unroll
    for (int rnd = 0; rnd < 2; ++rnd) {
      int prow = rnd * 8 + (lane >> 3);
      int j = lane & 7;
      unsigned base = (unsigned)(prow * 128);
      unsigned sw = ((unsigned)(prow & 7)) << 4;
      float* rowp = scoreW + (size_t)prow * L_ + ktg * (KTG * 64) + j * 4;
#pragma unroll
      for (int c = 0; c < 2 * KTG; ++c) {
        const char* pw = (const char*)ps[w][c >> 1];
        unsigned off = (base + (c & 1) * 64 + j * 8) ^ sw;
        ushort4 p4 = *reinterpret_cast<const ushort4*>(pw + off);
        f32x4 f;
        f[0] = bf2f(p4.x); f[1] = bf2f(p4.y); f[2] = bf2f(p4.z); f[3] = bf2f(p4.w);
        __builtin_nontemporal_store(f, reinterpret_cast<f32x4*>(rowp + c * 32));
      }
    }
  }

  // O store: stage via ps (free now), then 4x contiguous 1KB f32x4 NT stores
  {
    float* ow = reinterpret_cast<float*>(&ps[w][0][0]);
#pragma unroll
    for (int dt = 0; dt < 4; ++dt)
#pragma unroll
      for (int r = 0; r < 4; ++r)
        ow[(lg * 4 + r) * 64 + dt * 16 + lc] = o[dt][r];
    float* og = outp + ((size_t)bh * L_ + (size_t)qt * 64 + w * 16) * D_;
#pragma unroll
    for (int it = 0; it < 4; ++it) {
      int i = it * 64 + lane;
      int row = i >> 4, c4 = (i & 15) * 4;
      f32x4 f = *reinterpret_cast<const f32x4*>(ow + row * 64 + c4);
      __builtin_nontemporal_store(f, reinterpret_cast<f32x4*>(og + (size_t)row * D_ + c4));
    }
  }
}

// Drop columns whose mean <= 1e-5 (expected: none for this data).
__global__ void mask_fix(float* __restrict__ outp, float* __restrict__ score,
                         const float* __restrict__ colsum, const float* __restrict__ v) {
  __shared__ int drop_list[2048];
  __shared__ int ndrop;
  int bh = blockIdx.x;
  if (threadIdx.x == 0) ndrop = 0;
  __syncthreads();
  for (int c = threadIdx.x; c < L_; c += 256) {
    float mean = colsum[bh * L_ + c] * (1.0f / 2048.0f);
    if (!(mean > 1e-5f)) {
      int idx = atomicAdd(&ndrop, 1);
      drop_list[idx] = c;
    }
  }
  __syncthreads();
  int nd = ndrop;
  if (nd == 0) return;
  float* sc = score + (size_t)bh * L_ * L_;
  float* ob = outp + (size_t)bh * L_ * D_;
  const float* vb = v + (size_t)bh * L_ * D_;
  for (int i = 0; i < nd; ++i) {
    int k = drop_list[i];
    for (int idx = threadIdx.x; idx < L_ * D_; idx += 256) {
      int q = idx >> 6, d = idx & 63;
      ob[q * D_ + d] -= sc[(size_t)q * L_ + k] * vb[k * D_ + d];
    }
    __syncthreads();
  }
  for (int i = 0; i < nd; ++i) {
    int k = drop_list[i];
    for (int q = threadIdx.x; q < L_; q += 256) sc[(size_t)q * L_ + k] = 0.0f;
  }
}

extern "C" void kernel_launch(void* const* d_in, const int* in_sizes, int n_in,
                              void* d_out, int out_size, void* d_ws, size_t ws_size,
                              hipStream_t stream) {
  const float* q = (const float*)d_in[0];
  const float* k = (const float*)d_in[1];
  const float* v = (const float*)d_in[2];
  float* outp = (float*)d_out;
  float* score = outp + (size_t)BH_ * L_ * D_;

  unsigned short* wkf = (unsigned short*)d_ws;
  unsigned short* wvf = wkf + (size_t)BH_ * L_ * D_;
  float* colsum = (float*)(wvf + (size_t)BH_ * L_ * D_);

  prep<<<BH_ * NKT, 256, 0, stream>>>(k, v, wkf, wvf, colsum);
  attn_main<<<1024, 256, 0, stream>>>(q, wkf, wvf, outp, score, colsum);
  mask_fix<<<BH_, 256, 0, stream>>>(outp, score, colsum, v);
}

// Round 19
// 231.334 us; speedup vs baseline: 1.0167x; 1.0167x over previous
//
#include <hip/hip_runtime.h>

// B=2,H=16,L=2048,D=64 attention, outputs (out[B,H,L,D], score[B,H,L,L]) fp32.
// Budget: attn ~145us (sweep1 ~15 compute + sweep2 ~105 NT-store-bound at
// ~5 TB/s) + prep ~12 + mask ~5. Fill-rate floor would be ~120 total.
//
// v16 = v13 (best, 169.4us) with score stores switched from nt to sc1
// (device-scope): write-THROUGH the per-XCD L2 to the shared MALL/fabric --
// hypothesis: stream write-combines at fill rate (6.7 TB/s, like harness
// fills) without evicting L2-resident K/V frag tiles (unlike plain stores).
// Ledger: NT >> plain (+30..95us); 512B bursts +22us; KTG=4 dead; global-
// atomic colsum +60us (dead); K-staging/Q-prep/prep-coalescing neutral;
// 2rowx512B lane layout -10us (dead).

#define L_ 2048
#define D_ 64
#define BH_ 32
#define NKT 32
#define KTG 2

typedef __attribute__((ext_vector_type(8))) short bf16x8;
typedef __attribute__((ext_vector_type(4))) float f32x4;

__device__ __forceinline__ unsigned short f2bf(float f) {
  unsigned u = __builtin_bit_cast(unsigned, f);
  u = (u + 0x7FFFu + ((u >> 16) & 1u)) >> 16;  // RNE
  return (unsigned short)u;
}
__device__ __forceinline__ float bf2f(unsigned short h) {
  unsigned u = ((unsigned)h) << 16;
  return __builtin_bit_cast(float, u);
}
// device-scope store: write-through per-XCD L2 to shared level
__device__ __forceinline__ void store_sc1(float* p, f32x4 v) {
  asm volatile("global_store_dwordx4 %0, %1, off sc1" :: "v"(p), "v"(v) : "memory");
}

// prep: per 64x64 tile (1024 tiles = bh*32+kt):
//   K -> bf16 fragment-linear tile (el off = (t*2+h)*512 + lg*128 + lc*8 + j)
//   V -> VT (transpose) in the same fragment-linear layout (rows=d, cols=k)
// Built in LDS, then written with linear 16B/lane stores. Zeroes colsum.
__global__ void prep(const float* __restrict__ k, const float* __restrict__ v,
                     unsigned short* __restrict__ wkf, unsigned short* __restrict__ wvf,
                     float* __restrict__ colsum) {
  __shared__ __align__(16) unsigned short kimg[4096];
  __shared__ __align__(16) unsigned short vimg[4096];
  const int bid = blockIdx.x, tid = threadIdx.x;

  if (bid < 64) {
    float* cz = colsum + bid * 1024;
    for (int i = tid; i < 1024; i += 256) cz[i] = 0.0f;
  }

  const float* ks = k + (size_t)bid * 64 * D_;
  const float* vs = v + (size_t)bid * 64 * D_;

  // K tile -> frag-linear LDS image
#pragma unroll
  for (int it = 0; it < 2; ++it) {
    int e8 = it * 256 + tid;      // [0,512)
    int r = e8 >> 3;              // row 0..63
    int c0 = (e8 & 7) * 8;        // col 0,8,..,56
    float4 f0 = *reinterpret_cast<const float4*>(ks + r * D_ + c0);
    float4 f1 = *reinterpret_cast<const float4*>(ks + r * D_ + c0 + 4);
    int t = r >> 4, lc = r & 15, h = c0 >> 5, lg = (c0 & 31) >> 3;
    unsigned short* p = kimg + (t * 2 + h) * 512 + lg * 128 + lc * 8;
    ushort4 u0{f2bf(f0.x), f2bf(f0.y), f2bf(f0.z), f2bf(f0.w)};
    ushort4 u1{f2bf(f1.x), f2bf(f1.y), f2bf(f1.z), f2bf(f1.w)};
    *reinterpret_cast<ushort4*>(p) = u0;
    *reinterpret_cast<ushort4*>(p + 4) = u1;
  }

  // V tile -> transpose directly into frag-linear LDS image (rows=d, cols=k)
#pragma unroll
  for (int it = 0; it < 4; ++it) {
    int e4 = it * 256 + tid;       // 1024 float4
    int kk = e4 >> 4;              // k row 0..63
    int c = (e4 & 15) * 4;         // d cols c..c+3
    float4 f = *reinterpret_cast<const float4*>(vs + kk * D_ + c);
    int h = kk >> 5, lg = (kk >> 3) & 3, j = kk & 7;
    float ff[4] = {f.x, f.y, f.z, f.w};
#pragma unroll
    for (int x = 0; x < 4; ++x) {
      int d = c + x;
      int t = d >> 4, lc = d & 15;
      vimg[(t * 2 + h) * 512 + lg * 128 + lc * 8 + j] = f2bf(ff[x]);
    }
  }
  __syncthreads();

  // blast both images linearly: 16B/lane, full lines
  uint4* kd = reinterpret_cast<uint4*>(wkf + (size_t)bid * 4096);
  uint4* vd = reinterpret_cast<uint4*>(wvf + (size_t)bid * 4096);
  const uint4* ki = reinterpret_cast<const uint4*>(kimg);
  const uint4* vi = reinterpret_cast<const uint4*>(vimg);
#pragma unroll
  for (int it = 0; it < 2; ++it) {
    int idx = it * 256 + tid;      // 512 x 16B chunks per tile
    kd[idx] = ki[idx];
    vd[idx] = vi[idx];
  }
}

__launch_bounds__(256, 4)
__global__ void attn_main(const float* __restrict__ qf,
                          const unsigned short* __restrict__ wkf,
                          const unsigned short* __restrict__ wvf,
                          float* __restrict__ outp,
                          float* __restrict__ score,
                          float* __restrict__ colsum) {
  __shared__ __align__(16) unsigned short ps[4][KTG][1024];  // per-wave P stage
  __shared__ float cs_lds[2048];                             // block column sums

  const int tid = threadIdx.x;
  const int w = tid >> 6, lane = tid & 63;
  const int lg = lane >> 4, lc = lane & 15;

  // XCD-chunked swizzle: 1024 blocks -> 128 consecutive per XCD (4 bh per XCD)
  const int bid = (blockIdx.x & 7) * 128 + (blockIdx.x >> 3);
  const int bh = bid >> 5;
  const int qt = bid & 31;

  for (int i = tid; i < 2048; i += 256) cs_lds[i] = 0.0f;

  // Q fragments: fp32 global -> bf16 regs, fold 1/sqrt(64). 16 rows per wave.
  const float* qg = qf + ((size_t)bh * L_ + (size_t)qt * 64 + w * 16) * D_;
  bf16x8 aq[2];
#pragma unroll
  for (int h = 0; h < 2; ++h) {
    const float* r = qg + lc * D_ + h * 32 + lg * 8;
    float4 f0 = *reinterpret_cast<const float4*>(r);
    float4 f1 = *reinterpret_cast<const float4*>(r + 4);
    bf16x8 a;
    a[0] = (short)f2bf(f0.x * 0.125f); a[1] = (short)f2bf(f0.y * 0.125f);
    a[2] = (short)f2bf(f0.z * 0.125f); a[3] = (short)f2bf(f0.w * 0.125f);
    a[4] = (short)f2bf(f1.x * 0.125f); a[5] = (short)f2bf(f1.y * 0.125f);
    a[6] = (short)f2bf(f1.z * 0.125f); a[7] = (short)f2bf(f1.w * 0.125f);
    aq[h] = a;
  }

  __syncthreads();  // cs_lds init visible (only barrier until final flush)

  const unsigned short* kg = wkf + (size_t)bh * NKT * 4096 + lg * 128 + lc * 8;
  const unsigned short* vg = wvf + (size_t)bh * NKT * 4096 + lg * 128 + lc * 8;

  // ---------------- sweep 1: row sums of exp(s) (no max) ----------------
  float lp[4] = {0.f, 0.f, 0.f, 0.f};

#pragma unroll 2
  for (int kt = 0; kt < NKT; ++kt) {
    const unsigned short* kb = kg + kt * 4096;
    f32x4 s[4];
#pragma unroll
    for (int t = 0; t < 4; ++t) s[t] = f32x4{0.f, 0.f, 0.f, 0.f};
#pragma unroll
    for (int t = 0; t < 4; ++t) {
      bf16x8 b0 = *reinterpret_cast<const bf16x8*>(kb + (t * 2 + 0) * 512);
      bf16x8 b1 = *reinterpret_cast<const bf16x8*>(kb + (t * 2 + 1) * 512);
      s[t] = __builtin_amdgcn_mfma_f32_16x16x32_bf16(aq[0], b0, s[t], 0, 0, 0);
      s[t] = __builtin_amdgcn_mfma_f32_16x16x32_bf16(aq[1], b1, s[t], 0, 0, 0);
    }
#pragma unroll
    for (int t = 0; t < 4; ++t)
#pragma unroll
      for (int r = 0; r < 4; ++r) lp[r] += __expf(s[t][r]);
  }

  float linv[4];
#pragma unroll
  for (int r = 0; r < 4; ++r) {
    float v = lp[r];
    v += __shfl_xor(v, 1);
    v += __shfl_xor(v, 2);
    v += __shfl_xor(v, 4);
    v += __shfl_xor(v, 8);
    linv[r] = 1.0f / v;
  }

  // ------- sweep 2: kt-pairs; stage both P tiles, 512B/row burst stores --
  f32x4 o[4];
#pragma unroll
  for (int dt = 0; dt < 4; ++dt) o[dt] = f32x4{0.f, 0.f, 0.f, 0.f};

  float* scoreW = score + ((size_t)bh * L_ + (size_t)qt * 64 + w * 16) * L_;

#pragma unroll 1
  for (int ktg = 0; ktg < NKT / KTG; ++ktg) {
#pragma unroll
    for (int half = 0; half < KTG; ++half) {
      const int kt = ktg * KTG + half;
      const unsigned short* kb = kg + kt * 4096;
      char* pw = (char*)ps[w][half];

      f32x4 s[4];
#pragma unroll
      for (int t = 0; t < 4; ++t) s[t] = f32x4{0.f, 0.f, 0.f, 0.f};
#pragma unroll
      for (int t = 0; t < 4; ++t) {
        bf16x8 b0 = *reinterpret_cast<const bf16x8*>(kb + (t * 2 + 0) * 512);
        bf16x8 b1 = *reinterpret_cast<const bf16x8*>(kb + (t * 2 + 1) * 512);
        s[t] = __builtin_amdgcn_mfma_f32_16x16x32_bf16(aq[0], b0, s[t], 0, 0, 0);
        s[t] = __builtin_amdgcn_mfma_f32_16x16x32_bf16(aq[1], b1, s[t], 0, 0, 0);
      }

      // P = exp(s)*linv -> bf16 stage + column partials
      float ct[4] = {0.f, 0.f, 0.f, 0.f};
#pragma unroll
      for (int t = 0; t < 4; ++t)
#pragma unroll
        for (int r = 0; r < 4; ++r) {
          float p = __expf(s[t][r]) * linv[r];
          ct[t] += p;
          int prow = lg * 4 + r;
          unsigned off = ((unsigned)(prow * 128 + (t * 16 + lc) * 2)) ^ (((unsigned)(prow & 7)) << 4);
          *reinterpret_cast<unsigned short*>(pw + off) = f2bf(p);
        }

      // colsum: stagger t by wave to reduce cross-wave same-address atomics
#pragma unroll
      for (int t = 0; t < 4; ++t) {
        int tt = (t + w) & 3;
        float c = ct[tt];
        c += __shfl_xor(c, 16);
        c += __shfl_xor(c, 32);
        if (lane < 16) atomicAdd(&cs_lds[kt * 64 + tt * 16 + lane], c);
      }

      // P@V: A from this tile's stage, B direct from L2 frag tiles
#pragma unroll
      for (int kk = 0; kk < 2; ++kk) {
        unsigned o0 = ((unsigned)(lc * 128 + kk * 64 + lg * 16)) ^ (((unsigned)(lc & 7)) << 4);
        bf16x8 pa = *reinterpret_cast<const bf16x8*>(pw + o0);
        const unsigned short* vb = vg + kt * 4096 + kk * 512;
#pragma unroll
        for (int dt = 0; dt < 4; ++dt) {
          bf16x8 bv = *reinterpret_cast<const bf16x8*>(vb + dt * 1024);
          o[dt] = __builtin_amdgcn_mfma_f32_16x16x32_bf16(pa, bv, o[dt], 0, 0, 0);
        }
      }
    }

    // burst stores: per row-group, 4 consecutive chunk stores = 512B/row,
    // device-scope sc1 (write-through L2 to shared MALL)
#pragma unroll
    for (int rnd = 0; rnd < 2; ++rnd) {
      int prow = rnd * 8 + (lane >> 3);
      int j = lane & 7;
      unsigned base = (unsigned)(prow * 128);
      unsigned sw = ((unsigned)(prow & 7)) << 4;
      float* rowp = scoreW + (size_t)prow * L_ + ktg * (KTG * 64) + j * 4;
#pragma unroll
      for (int c = 0; c < 2 * KTG; ++c) {
        const char* pw = (const char*)ps[w][c >> 1];
        unsigned off = (base + (c & 1) * 64 + j * 8) ^ sw;
        ushort4 p4 = *reinterpret_cast<const ushort4*>(pw + off);
        f32x4 f;
        f[0] = bf2f(p4.x); f[1] = bf2f(p4.y); f[2] = bf2f(p4.z); f[3] = bf2f(p4.w);
        store_sc1(rowp + c * 32, f);
      }
    }
  }

  // O store: stage via ps (free now), then 4x contiguous 1KB f32x4 NT stores
  {
    float* ow = reinterpret_cast<float*>(&ps[w][0][0]);
#pragma unroll
    for (int dt = 0; dt < 4; ++dt)
#pragma unroll
      for (int r = 0; r < 4; ++r)
        ow[(lg * 4 + r) * 64 + dt * 16 + lc] = o[dt][r];
    float* og = outp + ((size_t)bh * L_ + (size_t)qt * 64 + w * 16) * D_;
#pragma unroll
    for (int it = 0; it < 4; ++it) {
      int i = it * 64 + lane;
      int row = i >> 4, c4 = (i & 15) * 4;
      f32x4 f = *reinterpret_cast<const f32x4*>(ow + row * 64 + c4);
      __builtin_nontemporal_store(f, reinterpret_cast<f32x4*>(og + (size_t)row * D_ + c4));
    }
  }

  // flush block-local colsums
  __syncthreads();
  for (int i = tid; i < L_; i += 256) atomicAdd(&colsum[bh * L_ + i], cs_lds[i]);
}

// Drop columns whose mean <= 1e-5 (expected: none for this data).
__global__ void mask_fix(float* __restrict__ outp, float* __restrict__ score,
                         const float* __restrict__ colsum, const float* __restrict__ v) {
  __shared__ int drop_list[2048];
  __shared__ int ndrop;
  int bh = blockIdx.x;
  if (threadIdx.x == 0) ndrop = 0;
  __syncthreads();
  for (int c = threadIdx.x; c < L_; c += 256) {
    float mean = colsum[bh * L_ + c] * (1.0f / 2048.0f);
    if (!(mean > 1e-5f)) {
      int idx = atomicAdd(&ndrop, 1);
      drop_list[idx] = c;
    }
  }
  __syncthreads();
  int nd = ndrop;
  if (nd == 0) return;
  float* sc = score + (size_t)bh * L_ * L_;
  float* ob = outp + (size_t)bh * L_ * D_;
  const float* vb = v + (size_t)bh * L_ * D_;
  for (int i = 0; i < nd; ++i) {
    int k = drop_list[i];
    for (int idx = threadIdx.x; idx < L_ * D_; idx += 256) {
      int q = idx >> 6, d = idx & 63;
      ob[q * D_ + d] -= sc[(size_t)q * L_ + k] * vb[k * D_ + d];
    }
    __syncthreads();
  }
  for (int i = 0; i < nd; ++i) {
    int k = drop_list[i];
    for (int q = threadIdx.x; q < L_; q += 256) sc[(size_t)q * L_ + k] = 0.0f;
  }
}

extern "C" void kernel_launch(void* const* d_in, const int* in_sizes, int n_in,
                              void* d_out, int out_size, void* d_ws, size_t ws_size,
                              hipStream_t stream) {
  const float* q = (const float*)d_in[0];
  const float* k = (const float*)d_in[1];
  const float* v = (const float*)d_in[2];
  float* outp = (float*)d_out;
  float* score = outp + (size_t)BH_ * L_ * D_;

  unsigned short* wkf = (unsigned short*)d_ws;
  unsigned short* wvf = wkf + (size_t)BH_ * L_ * D_;
  float* colsum = (float*)(wvf + (size_t)BH_ * L_ * D_);

  prep<<<BH_ * NKT, 256, 0, stream>>>(k, v, wkf, wvf, colsum);
  attn_main<<<1024, 256, 0, stream>>>(q, wkf, wvf, outp, score, colsum);
  mask_fix<<<BH_, 256, 0, stream>>>(outp, score, colsum, v);
}

// Round 20
// 169.124 us; speedup vs baseline: 1.3906x; 1.3678x over previous
//
#include <hip/hip_runtime.h>

// B=2,H=16,L=2048,D=64 attention, outputs (out[B,H,L,D], score[B,H,L,L]) fp32.
// FINAL (v13, measured 169.4us): the 19-round ledger pinned attn at the NT
// store-path ceiling (~4.8 TB/s effective for 554MB of 512B-burst rows).
// Store policy fully enumerated: plain 267-288 (L2 write-allocate thrash),
// sc1 231, nt 169 (best). Confirmed wins: 4 blk/CU occupancy (+65us), NT
// (+70..95), 512B row-bursts (+22), instr contiguity (+8%), LDS colsum
// (+60 vs global atomics). Neutral/negative: K or K+V LDS staging, Q-prep,
// prep-write coalescing, KTG=4, 2rowx512B lane layout, A/B chaining.

#define L_ 2048
#define D_ 64
#define BH_ 32
#define NKT 32
#define KTG 2

typedef __attribute__((ext_vector_type(8))) short bf16x8;
typedef __attribute__((ext_vector_type(4))) float f32x4;

__device__ __forceinline__ unsigned short f2bf(float f) {
  unsigned u = __builtin_bit_cast(unsigned, f);
  u = (u + 0x7FFFu + ((u >> 16) & 1u)) >> 16;  // RNE
  return (unsigned short)u;
}
__device__ __forceinline__ float bf2f(unsigned short h) {
  unsigned u = ((unsigned)h) << 16;
  return __builtin_bit_cast(float, u);
}

// prep: per 64x64 tile (1024 tiles = bh*32+kt):
//   K -> bf16 fragment-linear tile (el off = (t*2+h)*512 + lg*128 + lc*8 + j)
//   V -> VT (transpose) in the same fragment-linear layout (rows=d, cols=k)
// Built in LDS, then written with linear 16B/lane stores. Zeroes colsum.
__global__ void prep(const float* __restrict__ k, const float* __restrict__ v,
                     unsigned short* __restrict__ wkf, unsigned short* __restrict__ wvf,
                     float* __restrict__ colsum) {
  __shared__ __align__(16) unsigned short kimg[4096];
  __shared__ __align__(16) unsigned short vimg[4096];
  const int bid = blockIdx.x, tid = threadIdx.x;

  if (bid < 64) {
    float* cz = colsum + bid * 1024;
    for (int i = tid; i < 1024; i += 256) cz[i] = 0.0f;
  }

  const float* ks = k + (size_t)bid * 64 * D_;
  const float* vs = v + (size_t)bid * 64 * D_;

  // K tile -> frag-linear LDS image
#pragma unroll
  for (int it = 0; it < 2; ++it) {
    int e8 = it * 256 + tid;      // [0,512)
    int r = e8 >> 3;              // row 0..63
    int c0 = (e8 & 7) * 8;        // col 0,8,..,56
    float4 f0 = *reinterpret_cast<const float4*>(ks + r * D_ + c0);
    float4 f1 = *reinterpret_cast<const float4*>(ks + r * D_ + c0 + 4);
    int t = r >> 4, lc = r & 15, h = c0 >> 5, lg = (c0 & 31) >> 3;
    unsigned short* p = kimg + (t * 2 + h) * 512 + lg * 128 + lc * 8;
    ushort4 u0{f2bf(f0.x), f2bf(f0.y), f2bf(f0.z), f2bf(f0.w)};
    ushort4 u1{f2bf(f1.x), f2bf(f1.y), f2bf(f1.z), f2bf(f1.w)};
    *reinterpret_cast<ushort4*>(p) = u0;
    *reinterpret_cast<ushort4*>(p + 4) = u1;
  }

  // V tile -> transpose directly into frag-linear LDS image (rows=d, cols=k)
#pragma unroll
  for (int it = 0; it < 4; ++it) {
    int e4 = it * 256 + tid;       // 1024 float4
    int kk = e4 >> 4;              // k row 0..63
    int c = (e4 & 15) * 4;         // d cols c..c+3
    float4 f = *reinterpret_cast<const float4*>(vs + kk * D_ + c);
    int h = kk >> 5, lg = (kk >> 3) & 3, j = kk & 7;
    float ff[4] = {f.x, f.y, f.z, f.w};
#pragma unroll
    for (int x = 0; x < 4; ++x) {
      int d = c + x;
      int t = d >> 4, lc = d & 15;
      vimg[(t * 2 + h) * 512 + lg * 128 + lc * 8 + j] = f2bf(ff[x]);
    }
  }
  __syncthreads();

  // blast both images linearly: 16B/lane, full lines
  uint4* kd = reinterpret_cast<uint4*>(wkf + (size_t)bid * 4096);
  uint4* vd = reinterpret_cast<uint4*>(wvf + (size_t)bid * 4096);
  const uint4* ki = reinterpret_cast<const uint4*>(kimg);
  const uint4* vi = reinterpret_cast<const uint4*>(vimg);
#pragma unroll
  for (int it = 0; it < 2; ++it) {
    int idx = it * 256 + tid;      // 512 x 16B chunks per tile
    kd[idx] = ki[idx];
    vd[idx] = vi[idx];
  }
}

__launch_bounds__(256, 4)
__global__ void attn_main(const float* __restrict__ qf,
                          const unsigned short* __restrict__ wkf,
                          const unsigned short* __restrict__ wvf,
                          float* __restrict__ outp,
                          float* __restrict__ score,
                          float* __restrict__ colsum) {
  __shared__ __align__(16) unsigned short ps[4][KTG][1024];  // per-wave P stage
  __shared__ float cs_lds[2048];                             // block column sums

  const int tid = threadIdx.x;
  const int w = tid >> 6, lane = tid & 63;
  const int lg = lane >> 4, lc = lane & 15;

  // XCD-chunked swizzle: 1024 blocks -> 128 consecutive per XCD (4 bh per XCD)
  const int bid = (blockIdx.x & 7) * 128 + (blockIdx.x >> 3);
  const int bh = bid >> 5;
  const int qt = bid & 31;

  for (int i = tid; i < 2048; i += 256) cs_lds[i] = 0.0f;

  // Q fragments: fp32 global -> bf16 regs, fold 1/sqrt(64). 16 rows per wave.
  const float* qg = qf + ((size_t)bh * L_ + (size_t)qt * 64 + w * 16) * D_;
  bf16x8 aq[2];
#pragma unroll
  for (int h = 0; h < 2; ++h) {
    const float* r = qg + lc * D_ + h * 32 + lg * 8;
    float4 f0 = *reinterpret_cast<const float4*>(r);
    float4 f1 = *reinterpret_cast<const float4*>(r + 4);
    bf16x8 a;
    a[0] = (short)f2bf(f0.x * 0.125f); a[1] = (short)f2bf(f0.y * 0.125f);
    a[2] = (short)f2bf(f0.z * 0.125f); a[3] = (short)f2bf(f0.w * 0.125f);
    a[4] = (short)f2bf(f1.x * 0.125f); a[5] = (short)f2bf(f1.y * 0.125f);
    a[6] = (short)f2bf(f1.z * 0.125f); a[7] = (short)f2bf(f1.w * 0.125f);
    aq[h] = a;
  }

  __syncthreads();  // cs_lds init visible (only barrier until final flush)

  const unsigned short* kg = wkf + (size_t)bh * NKT * 4096 + lg * 128 + lc * 8;
  const unsigned short* vg = wvf + (size_t)bh * NKT * 4096 + lg * 128 + lc * 8;

  // ---------------- sweep 1: row sums of exp(s) (no max) ----------------
  float lp[4] = {0.f, 0.f, 0.f, 0.f};

#pragma unroll 2
  for (int kt = 0; kt < NKT; ++kt) {
    const unsigned short* kb = kg + kt * 4096;
    f32x4 s[4];
#pragma unroll
    for (int t = 0; t < 4; ++t) s[t] = f32x4{0.f, 0.f, 0.f, 0.f};
#pragma unroll
    for (int t = 0; t < 4; ++t) {
      bf16x8 b0 = *reinterpret_cast<const bf16x8*>(kb + (t * 2 + 0) * 512);
      bf16x8 b1 = *reinterpret_cast<const bf16x8*>(kb + (t * 2 + 1) * 512);
      s[t] = __builtin_amdgcn_mfma_f32_16x16x32_bf16(aq[0], b0, s[t], 0, 0, 0);
      s[t] = __builtin_amdgcn_mfma_f32_16x16x32_bf16(aq[1], b1, s[t], 0, 0, 0);
    }
#pragma unroll
    for (int t = 0; t < 4; ++t)
#pragma unroll
      for (int r = 0; r < 4; ++r) lp[r] += __expf(s[t][r]);
  }

  float linv[4];
#pragma unroll
  for (int r = 0; r < 4; ++r) {
    float v = lp[r];
    v += __shfl_xor(v, 1);
    v += __shfl_xor(v, 2);
    v += __shfl_xor(v, 4);
    v += __shfl_xor(v, 8);
    linv[r] = 1.0f / v;
  }

  // ------- sweep 2: kt-pairs; stage both P tiles, 512B/row burst stores --
  f32x4 o[4];
#pragma unroll
  for (int dt = 0; dt < 4; ++dt) o[dt] = f32x4{0.f, 0.f, 0.f, 0.f};

  float* scoreW = score + ((size_t)bh * L_ + (size_t)qt * 64 + w * 16) * L_;

#pragma unroll 1
  for (int ktg = 0; ktg < NKT / KTG; ++ktg) {
#pragma unroll
    for (int half = 0; half < KTG; ++half) {
      const int kt = ktg * KTG + half;
      const unsigned short* kb = kg + kt * 4096;
      char* pw = (char*)ps[w][half];

      f32x4 s[4];
#pragma unroll
      for (int t = 0; t < 4; ++t) s[t] = f32x4{0.f, 0.f, 0.f, 0.f};
#pragma unroll
      for (int t = 0; t < 4; ++t) {
        bf16x8 b0 = *reinterpret_cast<const bf16x8*>(kb + (t * 2 + 0) * 512);
        bf16x8 b1 = *reinterpret_cast<const bf16x8*>(kb + (t * 2 + 1) * 512);
        s[t] = __builtin_amdgcn_mfma_f32_16x16x32_bf16(aq[0], b0, s[t], 0, 0, 0);
        s[t] = __builtin_amdgcn_mfma_f32_16x16x32_bf16(aq[1], b1, s[t], 0, 0, 0);
      }

      // P = exp(s)*linv -> bf16 stage + column partials
      float ct[4] = {0.f, 0.f, 0.f, 0.f};
#pragma unroll
      for (int t = 0; t < 4; ++t)
#pragma unroll
        for (int r = 0; r < 4; ++r) {
          float p = __expf(s[t][r]) * linv[r];
          ct[t] += p;
          int prow = lg * 4 + r;
          unsigned off = ((unsigned)(prow * 128 + (t * 16 + lc) * 2)) ^ (((unsigned)(prow & 7)) << 4);
          *reinterpret_cast<unsigned short*>(pw + off) = f2bf(p);
        }

      // colsum: stagger t by wave to reduce cross-wave same-address atomics
#pragma unroll
      for (int t = 0; t < 4; ++t) {
        int tt = (t + w) & 3;
        float c = ct[tt];
        c += __shfl_xor(c, 16);
        c += __shfl_xor(c, 32);
        if (lane < 16) atomicAdd(&cs_lds[kt * 64 + tt * 16 + lane], c);
      }

      // P@V: A from this tile's stage, B direct from L2 frag tiles
#pragma unroll
      for (int kk = 0; kk < 2; ++kk) {
        unsigned o0 = ((unsigned)(lc * 128 + kk * 64 + lg * 16)) ^ (((unsigned)(lc & 7)) << 4);
        bf16x8 pa = *reinterpret_cast<const bf16x8*>(pw + o0);
        const unsigned short* vb = vg + kt * 4096 + kk * 512;
#pragma unroll
        for (int dt = 0; dt < 4; ++dt) {
          bf16x8 bv = *reinterpret_cast<const bf16x8*>(vb + dt * 1024);
          o[dt] = __builtin_amdgcn_mfma_f32_16x16x32_bf16(pa, bv, o[dt], 0, 0, 0);
        }
      }
    }

    // burst stores: per row-group, 4 consecutive chunk stores = 512B/row, NT
#pragma unroll
    for (int rnd = 0; rnd < 2; ++rnd) {
      int prow = rnd * 8 + (lane >> 3);
      int j = lane & 7;
      unsigned base = (unsigned)(prow * 128);
      unsigned sw = ((unsigned)(prow & 7)) << 4;
      float* rowp = scoreW + (size_t)prow * L_ + ktg * (KTG * 64) + j * 4;
#pragma unroll
      for (int c = 0; c < 2 * KTG; ++c) {
        const char* pw = (const char*)ps[w][c >> 1];
        unsigned off = (base + (c & 1) * 64 + j * 8) ^ sw;
        ushort4 p4 = *reinterpret_cast<const ushort4*>(pw + off);
        f32x4 f;
        f[0] = bf2f(p4.x); f[1] = bf2f(p4.y); f[2] = bf2f(p4.z); f[3] = bf2f(p4.w);
        __builtin_nontemporal_store(f, reinterpret_cast<f32x4*>(rowp + c * 32));
      }
    }
  }

  // O store: stage via ps (free now), then 4x contiguous 1KB f32x4 NT stores
  {
    float* ow = reinterpret_cast<float*>(&ps[w][0][0]);
#pragma unroll
    for (int dt = 0; dt < 4; ++dt)
#pragma unroll
      for (int r = 0; r < 4; ++r)
        ow[(lg * 4 + r) * 64 + dt * 16 + lc] = o[dt][r];
    float* og = outp + ((size_t)bh * L_ + (size_t)qt * 64 + w * 16) * D_;
#pragma unroll
    for (int it = 0; it < 4; ++it) {
      int i = it * 64 + lane;
      int row = i >> 4, c4 = (i & 15) * 4;
      f32x4 f = *reinterpret_cast<const f32x4*>(ow + row * 64 + c4);
      __builtin_nontemporal_store(f, reinterpret_cast<f32x4*>(og + (size_t)row * D_ + c4));
    }
  }

  // flush block-local colsums
  __syncthreads();
  for (int i = tid; i < L_; i += 256) atomicAdd(&colsum[bh * L_ + i], cs_lds[i]);
}

// Drop columns whose mean <= 1e-5 (expected: none for this data).
__global__ void mask_fix(float* __restrict__ outp, float* __restrict__ score,
                         const float* __restrict__ colsum, const float* __restrict__ v) {
  __shared__ int drop_list[2048];
  __shared__ int ndrop;
  int bh = blockIdx.x;
  if (threadIdx.x == 0) ndrop = 0;
  __syncthreads();
  for (int c = threadIdx.x; c < L_; c += 256) {
    float mean = colsum[bh * L_ + c] * (1.0f / 2048.0f);
    if (!(mean > 1e-5f)) {
      int idx = atomicAdd(&ndrop, 1);
      drop_list[idx] = c;
    }
  }
  __syncthreads();
  int nd = ndrop;
  if (nd == 0) return;
  float* sc = score + (size_t)bh * L_ * L_;
  float* ob = outp + (size_t)bh * L_ * D_;
  const float* vb = v + (size_t)bh * L_ * D_;
  for (int i = 0; i < nd; ++i) {
    int k = drop_list[i];
    for (int idx = threadIdx.x; idx < L_ * D_; idx += 256) {
      int q = idx >> 6, d = idx & 63;
      ob[q * D_ + d] -= sc[(size_t)q * L_ + k] * vb[k * D_ + d];
    }
    __syncthreads();
  }
  for (int i = 0; i < nd; ++i) {
    int k = drop_list[i];
    for (int q = threadIdx.x; q < L_; q += 256) sc[(size_t)q * L_ + k] = 0.0f;
  }
}

extern "C" void kernel_launch(void* const* d_in, const int* in_sizes, int n_in,
                              void* d_out, int out_size, void* d_ws, size_t ws_size,
                              hipStream_t stream) {
  const float* q = (const float*)d_in[0];
  const float* k = (const float*)d_in[1];
  const float* v = (const float*)d_in[2];
  float* outp = (float*)d_out;
  float* score = outp + (size_t)BH_ * L_ * D_;

  unsigned short* wkf = (unsigned short*)d_ws;
  unsigned short* wvf = wkf + (size_t)BH_ * L_ * D_;
  float* colsum = (float*)(wvf + (size_t)BH_ * L_ * D_);

  prep<<<BH_ * NKT, 256, 0, stream>>>(k, v, wkf, wvf, colsum);
  attn_main<<<1024, 256, 0, stream>>>(q, wkf, wvf, outp, score, colsum);
  mask_fix<<<BH_, 256, 0, stream>>>(outp, score, colsum, v);
}